// Round 1
// baseline (296.353 us; speedup 1.0000x reference)
//
#include <hip/hip_runtime.h>
#include <hip/hip_bf16.h>

typedef __bf16 bf16;
typedef __bf16 bf16x4 __attribute__((ext_vector_type(4)));
typedef __bf16 bf16x8 __attribute__((ext_vector_type(8)));
typedef float f32x4 __attribute__((ext_vector_type(4)));

#define DIM 768
#define HW 1024          // 32*32
#define BATCH 16
#define M_TOTAL (BATCH * HW)   // 16384

// ---------------- weight convert: f32 -> bf16 ----------------
__global__ void wcvt_kernel(const float4* __restrict__ w, bf16x4* __restrict__ o) {
    int i = blockIdx.x * 256 + threadIdx.x;
    float4 v = w[i];
    bf16x4 r = { (bf16)v.x, (bf16)v.y, (bf16)v.z, (bf16)v.w };
    o[i] = r;
}

// ---------------- transpose + convert: x[16][768][1024] f32 -> xb[16384][768] bf16 ----------------
__global__ void transpose_cvt_kernel(const float* __restrict__ x, bf16* __restrict__ xb) {
    __shared__ float tile[32][33];
    const int b = blockIdx.z;
    const int hw0 = blockIdx.x * 32;
    const int c0 = blockIdx.y * 32;
    const int tx = threadIdx.x, ty = threadIdx.y;  // 32 x 8

    const float* src = x + ((size_t)b * DIM + c0) * HW + hw0;
#pragma unroll
    for (int j = 0; j < 4; j++)
        tile[ty + 8 * j][tx] = src[(size_t)(ty + 8 * j) * HW + tx];
    __syncthreads();
    bf16* dst = xb + ((size_t)b * HW + hw0) * DIM + c0;
#pragma unroll
    for (int j = 0; j < 4; j++)
        dst[(size_t)(ty + 8 * j) * DIM + tx] = (bf16)tile[tx][ty + 8 * j];
}

// ---------------- GEMM: C[M][768] = A[M][768] * W[768][768]^T (+bias) ----------------
// MODE 0: write bf16 row-major [n][768] (pre-LN activations incl. bias)
// MODE 1: write f32 NCHW out[b][o][hw] (+bias)
template <int MODE>
__global__ __launch_bounds__(256) void gemm_kernel(
    const bf16* __restrict__ A,   // [M][768] row-major
    const bf16* __restrict__ Bw,  // [768][768] = W[o][c]
    const float* __restrict__ bias,
    void* __restrict__ out)
{
    constexpr int K = DIM;
    __shared__ bf16 As[128][32];
    __shared__ bf16 Bs[128][32];

    const int t = threadIdx.x;
    const int lane = t & 63;
    const int wave = t >> 6;
    const int wr = wave >> 1, wc = wave & 1;
    const int m0 = blockIdx.x * 128;
    const int n0 = blockIdx.y * 128;

    f32x4 acc[4][4] = {};

    const int srow = t >> 2;        // 0..63
    const int skc = (t & 3) * 8;    // 0,8,16,24
    const int fr = lane & 15;
    const int kb = (lane >> 4) * 4;

    for (int k0 = 0; k0 < K; k0 += 32) {
        // stage A and B tiles via async global->LDS (16B/lane)
#pragma unroll
        for (int i = 0; i < 2; i++) {
            const int r = srow + i * 64;
            __builtin_amdgcn_global_load_lds(
                (const __attribute__((address_space(1))) void*)(A + (size_t)(m0 + r) * K + k0 + skc),
                (__attribute__((address_space(3))) void*)&As[r][skc], 16, 0, 0);
            __builtin_amdgcn_global_load_lds(
                (const __attribute__((address_space(1))) void*)(Bw + (size_t)(n0 + r) * K + k0 + skc),
                (__attribute__((address_space(3))) void*)&Bs[r][skc], 16, 0, 0);
        }
        __syncthreads();

        bf16x8 aF[4], bF[4];
#pragma unroll
        for (int mi = 0; mi < 4; mi++) {
            const bf16* p = &As[wr * 64 + mi * 16 + fr][kb];
            bf16x4 lo = *(const bf16x4*)p;
            bf16x4 hi = *(const bf16x4*)(p + 16);
            aF[mi] = __builtin_shufflevector(lo, hi, 0, 1, 2, 3, 4, 5, 6, 7);
        }
#pragma unroll
        for (int ni = 0; ni < 4; ni++) {
            const bf16* p = &Bs[wc * 64 + ni * 16 + fr][kb];
            bf16x4 lo = *(const bf16x4*)p;
            bf16x4 hi = *(const bf16x4*)(p + 16);
            bF[ni] = __builtin_shufflevector(lo, hi, 0, 1, 2, 3, 4, 5, 6, 7);
        }
#pragma unroll
        for (int mi = 0; mi < 4; mi++)
#pragma unroll
            for (int ni = 0; ni < 4; ni++)
                acc[mi][ni] = __builtin_amdgcn_mfma_f32_16x16x32_bf16(aF[mi], bF[ni], acc[mi][ni], 0, 0, 0);
        __syncthreads();
    }

    const int fq = lane >> 4;  // 0..3
    if (MODE == 0) {
        bf16* o = (bf16*)out;
#pragma unroll
        for (int mi = 0; mi < 4; mi++) {
            const int row = m0 + wr * 64 + mi * 16 + fq * 4;
#pragma unroll
            for (int ni = 0; ni < 4; ni++) {
                const int col = n0 + wc * 64 + ni * 16 + fr;
                const float bv = bias[col];
#pragma unroll
                for (int r = 0; r < 4; r++)
                    o[(size_t)(row + r) * DIM + col] = (bf16)(acc[mi][ni][r] + bv);
            }
        }
    } else {
        float* o = (float*)out;
#pragma unroll
        for (int mi = 0; mi < 4; mi++) {
            const int n_base = m0 + wr * 64 + mi * 16 + fq * 4;
            const int b = n_base >> 10;
            const int hw = n_base & 1023;
#pragma unroll
            for (int ni = 0; ni < 4; ni++) {
                const int col = n0 + wc * 64 + ni * 16 + fr;
                const float bv = bias[col];
                f32x4 v = acc[mi][ni] + bv;
                *(f32x4*)(o + ((size_t)b * DIM + col) * HW + hw) = v;
            }
        }
    }
}

// ---------------- LayerNorm + exact GELU, in-place on bf16 rows ----------------
__global__ __launch_bounds__(256) void ln_gelu_kernel(
    bf16* __restrict__ h, const float* __restrict__ g, const float* __restrict__ beta)
{
    const int wave = threadIdx.x >> 6;
    const int lane = threadIdx.x & 63;
    const int n = blockIdx.x * 4 + wave;
    bf16* row = h + (size_t)n * DIM;

    float v[12];
    float s = 0.f, ss = 0.f;
#pragma unroll
    for (int j = 0; j < 3; j++) {
        bf16x4 x = *(const bf16x4*)(row + j * 256 + lane * 4);
#pragma unroll
        for (int i = 0; i < 4; i++) {
            float f = (float)x[i];
            v[j * 4 + i] = f;
            s += f;
            ss += f * f;
        }
    }
#pragma unroll
    for (int off = 32; off > 0; off >>= 1) {
        s += __shfl_xor(s, off);
        ss += __shfl_xor(ss, off);
    }
    const float mu = s * (1.f / DIM);
    const float var = ss * (1.f / DIM) - mu * mu;
    const float rstd = rsqrtf(var + 1e-6f);

#pragma unroll
    for (int j = 0; j < 3; j++) {
        bf16x4 r;
#pragma unroll
        for (int i = 0; i < 4; i++) {
            const int c = j * 256 + lane * 4 + i;
            float y = (v[j * 4 + i] - mu) * rstd * g[c] + beta[c];
            y = 0.5f * y * (1.f + erff(y * 0.70710678118f));
            r[i] = (bf16)y;
        }
        *(bf16x4*)(row + j * 256 + lane * 4) = r;
    }
}

extern "C" void kernel_launch(void* const* d_in, const int* in_sizes, int n_in,
                              void* d_out, int out_size, void* d_ws, size_t ws_size,
                              hipStream_t stream) {
    const float* x   = (const float*)d_in[0];
    const float* W1  = (const float*)d_in[1];
    const float* b1  = (const float*)d_in[2];
    const float* g1  = (const float*)d_in[3];
    const float* be1 = (const float*)d_in[4];
    const float* W2  = (const float*)d_in[5];
    const float* b2  = (const float*)d_in[6];
    const float* g2  = (const float*)d_in[7];
    const float* be2 = (const float*)d_in[8];
    const float* W3  = (const float*)d_in[9];
    const float* b3  = (const float*)d_in[10];
    float* out = (float*)d_out;

    bf16* Wb1  = (bf16*)d_ws;
    bf16* Wb2  = Wb1 + (size_t)DIM * DIM;
    bf16* Wb3  = Wb2 + (size_t)DIM * DIM;
    bf16* buf0 = Wb3 + (size_t)DIM * DIM;          // 16384*768 bf16
    bf16* buf1 = buf0 + (size_t)M_TOTAL * DIM;

    // weights -> bf16
    wcvt_kernel<<<576, 256, 0, stream>>>((const float4*)W1, (bf16x4*)Wb1);
    wcvt_kernel<<<576, 256, 0, stream>>>((const float4*)W2, (bf16x4*)Wb2);
    wcvt_kernel<<<576, 256, 0, stream>>>((const float4*)W3, (bf16x4*)Wb3);

    // x NCHW -> [n][c] bf16
    transpose_cvt_kernel<<<dim3(32, 24, 16), dim3(32, 8), 0, stream>>>(x, buf0);

    dim3 ggrid(M_TOTAL / 128, DIM / 128);
    // layer 1
    gemm_kernel<0><<<ggrid, 256, 0, stream>>>(buf0, Wb1, b1, buf1);
    ln_gelu_kernel<<<M_TOTAL / 4, 256, 0, stream>>>(buf1, g1, be1);
    // layer 2
    gemm_kernel<0><<<ggrid, 256, 0, stream>>>(buf1, Wb2, b2, buf0);
    ln_gelu_kernel<<<M_TOTAL / 4, 256, 0, stream>>>(buf0, g2, be2);
    // layer 3 -> NCHW f32 output
    gemm_kernel<1><<<ggrid, 256, 0, stream>>>(buf0, Wb3, b3, out);
}

// Round 2
// 171.953 us; speedup vs baseline: 1.7235x; 1.7235x over previous
//
#include <hip/hip_runtime.h>
#include <hip/hip_bf16.h>

typedef __bf16 bf16;
typedef __bf16 bf16x4 __attribute__((ext_vector_type(4)));
typedef __bf16 bf16x8 __attribute__((ext_vector_type(8)));
typedef float f32x4 __attribute__((ext_vector_type(4)));

#define DIM 768
#define HW 1024          // 32*32
#define BATCH 16
#define M_TOTAL (BATCH * HW)   // 16384

// ---------------- weight convert: f32 -> bf16 ----------------
__global__ void wcvt_kernel(const float4* __restrict__ w, bf16x4* __restrict__ o) {
    int i = blockIdx.x * 256 + threadIdx.x;
    float4 v = w[i];
    bf16x4 r = { (bf16)v.x, (bf16)v.y, (bf16)v.z, (bf16)v.w };
    o[i] = r;
}

// ---------------- transpose + convert: x[16][768][1024] f32 -> xb[16384][768] bf16 ----------------
__global__ void transpose_cvt_kernel(const float* __restrict__ x, bf16* __restrict__ xb) {
    __shared__ float tile[32][33];
    const int b = blockIdx.z;
    const int hw0 = blockIdx.x * 32;
    const int c0 = blockIdx.y * 32;
    const int tx = threadIdx.x, ty = threadIdx.y;  // 32 x 8

    const float* src = x + ((size_t)b * DIM + c0) * HW + hw0;
#pragma unroll
    for (int j = 0; j < 4; j++)
        tile[ty + 8 * j][tx] = src[(size_t)(ty + 8 * j) * HW + tx];
    __syncthreads();
    bf16* dst = xb + ((size_t)b * HW + hw0) * DIM + c0;
#pragma unroll
    for (int j = 0; j < 4; j++)
        dst[(size_t)(ty + 8 * j) * DIM + tx] = (bf16)tile[tx][ty + 8 * j];
}

// ---------------- GEMM: C[M][768] = A[M][768] * W[768][768]^T (+bias) ----------------
// LDS tiles are XOR-swizzled at 16B-block granularity: logical 16B block g of
// row r is stored at block position g ^ ((r>>1)&3). LDS writes stay linear
// (global_load_lds requirement); the global SOURCE address is pre-swizzled,
// and fragment reads apply the same XOR. Involution: mask sources addr bits
// 7-8, targets bits 4-5 only.
// MODE 0: write bf16 row-major [n][768] (pre-LN activations incl. bias)
// MODE 1: write f32 NCHW out[b][o][hw] (+bias)
template <int MODE>
__global__ __launch_bounds__(256) void gemm_kernel(
    const bf16* __restrict__ A,   // [M][768] row-major
    const bf16* __restrict__ Bw,  // [768][768] = W[o][c]
    const float* __restrict__ bias,
    void* __restrict__ out)
{
    constexpr int K = DIM;
    __shared__ bf16 As[128][32];
    __shared__ bf16 Bs[128][32];

    const int t = threadIdx.x;
    const int lane = t & 63;
    const int wave = t >> 6;
    const int wr = wave >> 1, wc = wave & 1;
    const int m0 = blockIdx.x * 128;
    const int n0 = blockIdx.y * 128;

    f32x4 acc[4][4] = {};

    const int srow = t >> 2;        // 0..63
    const int glin = t & 3;         // linear 16B block within row
    const int fr = lane & 15;
    const int kb = (lane >> 4) * 4; // 0,4,8,12

    // fragment-read swizzled element offsets (depend only on lane)
    const int s_rd = (fr >> 1) & 3;
    const int g0 = kb >> 3;         // 0,0,1,1
    const int rem = kb & 7;         // 0,4,0,4
    const int offLo = ((g0 ^ s_rd) << 3) + rem;
    const int offHi = (((g0 + 2) ^ s_rd) << 3) + rem;

    for (int k0 = 0; k0 < K; k0 += 32) {
        // stage A and B tiles via async global->LDS (16B/lane), source pre-swizzled
#pragma unroll
        for (int i = 0; i < 2; i++) {
            const int r = srow + i * 64;
            const int gsrc = glin ^ ((r >> 1) & 3);
            __builtin_amdgcn_global_load_lds(
                (const __attribute__((address_space(1))) void*)(A + (size_t)(m0 + r) * K + k0 + gsrc * 8),
                (__attribute__((address_space(3))) void*)&As[r][glin * 8], 16, 0, 0);
            __builtin_amdgcn_global_load_lds(
                (const __attribute__((address_space(1))) void*)(Bw + (size_t)(n0 + r) * K + k0 + gsrc * 8),
                (__attribute__((address_space(3))) void*)&Bs[r][glin * 8], 16, 0, 0);
        }
        __syncthreads();

        bf16x8 aF[4], bF[4];
#pragma unroll
        for (int mi = 0; mi < 4; mi++) {
            const bf16* p = &As[wr * 64 + mi * 16 + fr][0];
            bf16x4 lo = *(const bf16x4*)(p + offLo);
            bf16x4 hi = *(const bf16x4*)(p + offHi);
            aF[mi] = __builtin_shufflevector(lo, hi, 0, 1, 2, 3, 4, 5, 6, 7);
        }
#pragma unroll
        for (int ni = 0; ni < 4; ni++) {
            const bf16* p = &Bs[wc * 64 + ni * 16 + fr][0];
            bf16x4 lo = *(const bf16x4*)(p + offLo);
            bf16x4 hi = *(const bf16x4*)(p + offHi);
            bF[ni] = __builtin_shufflevector(lo, hi, 0, 1, 2, 3, 4, 5, 6, 7);
        }
#pragma unroll
        for (int mi = 0; mi < 4; mi++)
#pragma unroll
            for (int ni = 0; ni < 4; ni++)
                acc[mi][ni] = __builtin_amdgcn_mfma_f32_16x16x32_bf16(aF[mi], bF[ni], acc[mi][ni], 0, 0, 0);
        __syncthreads();
    }

    const int fq = lane >> 4;  // 0..3
    if (MODE == 0) {
        bf16* o = (bf16*)out;
#pragma unroll
        for (int mi = 0; mi < 4; mi++) {
            const int row = m0 + wr * 64 + mi * 16 + fq * 4;
#pragma unroll
            for (int ni = 0; ni < 4; ni++) {
                const int col = n0 + wc * 64 + ni * 16 + fr;
                const float bv = bias[col];
#pragma unroll
                for (int r = 0; r < 4; r++)
                    o[(size_t)(row + r) * DIM + col] = (bf16)(acc[mi][ni][r] + bv);
            }
        }
    } else {
        float* o = (float*)out;
#pragma unroll
        for (int mi = 0; mi < 4; mi++) {
            const int n_base = m0 + wr * 64 + mi * 16 + fq * 4;
            const int b = n_base >> 10;
            const int hw = n_base & 1023;
#pragma unroll
            for (int ni = 0; ni < 4; ni++) {
                const int col = n0 + wc * 64 + ni * 16 + fr;
                const float bv = bias[col];
                f32x4 v = acc[mi][ni] + bv;
                *(f32x4*)(o + ((size_t)b * DIM + col) * HW + hw) = v;
            }
        }
    }
}

// ---------------- LayerNorm + exact GELU, in-place on bf16 rows ----------------
__global__ __launch_bounds__(256) void ln_gelu_kernel(
    bf16* __restrict__ h, const float* __restrict__ g, const float* __restrict__ beta)
{
    const int wave = threadIdx.x >> 6;
    const int lane = threadIdx.x & 63;
    const int n = blockIdx.x * 4 + wave;
    bf16* row = h + (size_t)n * DIM;

    float v[12];
    float s = 0.f, ss = 0.f;
#pragma unroll
    for (int j = 0; j < 3; j++) {
        bf16x4 x = *(const bf16x4*)(row + j * 256 + lane * 4);
#pragma unroll
        for (int i = 0; i < 4; i++) {
            float f = (float)x[i];
            v[j * 4 + i] = f;
            s += f;
            ss += f * f;
        }
    }
#pragma unroll
    for (int off = 32; off > 0; off >>= 1) {
        s += __shfl_xor(s, off);
        ss += __shfl_xor(ss, off);
    }
    const float mu = s * (1.f / DIM);
    const float var = ss * (1.f / DIM) - mu * mu;
    const float rstd = rsqrtf(var + 1e-6f);

#pragma unroll
    for (int j = 0; j < 3; j++) {
        bf16x4 r;
#pragma unroll
        for (int i = 0; i < 4; i++) {
            const int c = j * 256 + lane * 4 + i;
            float y = (v[j * 4 + i] - mu) * rstd * g[c] + beta[c];
            y = 0.5f * y * (1.f + erff(y * 0.70710678118f));
            r[i] = (bf16)y;
        }
        *(bf16x4*)(row + j * 256 + lane * 4) = r;
    }
}

extern "C" void kernel_launch(void* const* d_in, const int* in_sizes, int n_in,
                              void* d_out, int out_size, void* d_ws, size_t ws_size,
                              hipStream_t stream) {
    const float* x   = (const float*)d_in[0];
    const float* W1  = (const float*)d_in[1];
    const float* b1  = (const float*)d_in[2];
    const float* g1  = (const float*)d_in[3];
    const float* be1 = (const float*)d_in[4];
    const float* W2  = (const float*)d_in[5];
    const float* b2  = (const float*)d_in[6];
    const float* g2  = (const float*)d_in[7];
    const float* be2 = (const float*)d_in[8];
    const float* W3  = (const float*)d_in[9];
    const float* b3  = (const float*)d_in[10];
    float* out = (float*)d_out;

    bf16* Wb1  = (bf16*)d_ws;
    bf16* Wb2  = Wb1 + (size_t)DIM * DIM;
    bf16* Wb3  = Wb2 + (size_t)DIM * DIM;
    bf16* buf0 = Wb3 + (size_t)DIM * DIM;          // 16384*768 bf16
    bf16* buf1 = buf0 + (size_t)M_TOTAL * DIM;

    // weights -> bf16
    wcvt_kernel<<<576, 256, 0, stream>>>((const float4*)W1, (bf16x4*)Wb1);
    wcvt_kernel<<<576, 256, 0, stream>>>((const float4*)W2, (bf16x4*)Wb2);
    wcvt_kernel<<<576, 256, 0, stream>>>((const float4*)W3, (bf16x4*)Wb3);

    // x NCHW -> [n][c] bf16
    transpose_cvt_kernel<<<dim3(32, 24, 16), dim3(32, 8), 0, stream>>>(x, buf0);

    dim3 ggrid(M_TOTAL / 128, DIM / 128);
    // layer 1
    gemm_kernel<0><<<ggrid, 256, 0, stream>>>(buf0, Wb1, b1, buf1);
    ln_gelu_kernel<<<M_TOTAL / 4, 256, 0, stream>>>(buf1, g1, be1);
    // layer 2
    gemm_kernel<0><<<ggrid, 256, 0, stream>>>(buf1, Wb2, b2, buf0);
    ln_gelu_kernel<<<M_TOTAL / 4, 256, 0, stream>>>(buf0, g2, be2);
    // layer 3 -> NCHW f32 output
    gemm_kernel<1><<<ggrid, 256, 0, stream>>>(buf0, Wb3, b3, out);
}

// Round 3
// 171.074 us; speedup vs baseline: 1.7323x; 1.0051x over previous
//
#include <hip/hip_runtime.h>
#include <hip/hip_bf16.h>

typedef __bf16 bf16;
typedef __bf16 bf16x4 __attribute__((ext_vector_type(4)));
typedef __bf16 bf16x8 __attribute__((ext_vector_type(8)));
typedef float f32x4 __attribute__((ext_vector_type(4)));

#define DIM 768
#define HW 1024          // 32*32
#define BATCH 16
#define M_TOTAL (BATCH * HW)   // 16384
#define NT 24                  // K-steps: 768/32

// ---------------- weight convert: f32 -> bf16 (all 3 in one launch) ----------------
__global__ void wcvt3_kernel(const float4* __restrict__ w1, const float4* __restrict__ w2,
                             const float4* __restrict__ w3,
                             bf16x4* __restrict__ o1, bf16x4* __restrict__ o2,
                             bf16x4* __restrict__ o3) {
    const int b = blockIdx.x;            // 0..1727
    const int which = b / 576;
    const int i = (b % 576) * 256 + threadIdx.x;
    const float4* w = which == 0 ? w1 : which == 1 ? w2 : w3;
    bf16x4* o = which == 0 ? o1 : which == 1 ? o2 : o3;
    float4 v = w[i];
    bf16x4 r = { (bf16)v.x, (bf16)v.y, (bf16)v.z, (bf16)v.w };
    o[i] = r;
}

// ---------------- transpose + convert: x[16][768][1024] f32 -> xb[16384][768] bf16 ----------------
__global__ void transpose_cvt_kernel(const float* __restrict__ x, bf16* __restrict__ xb) {
    __shared__ float tile[32][33];
    const int b = blockIdx.z;
    const int hw0 = blockIdx.x * 32;
    const int c0 = blockIdx.y * 32;
    const int tx = threadIdx.x, ty = threadIdx.y;  // 32 x 8

    const float* src = x + ((size_t)b * DIM + c0) * HW + hw0;
#pragma unroll
    for (int j = 0; j < 4; j++)
        tile[ty + 8 * j][tx] = src[(size_t)(ty + 8 * j) * HW + tx];
    __syncthreads();
    bf16* dst = xb + ((size_t)b * HW + hw0) * DIM + c0;
#pragma unroll
    for (int j = 0; j < 4; j++)
        dst[(size_t)(ty + 8 * j) * DIM + tx] = (bf16)tile[tx][ty + 8 * j];
}

// ---------------- GEMM: C[M][768] = A[M][768] * W[768][768]^T (+bias) ----------------
// LDS 16B-block XOR swizzle (g ^= (r>>1)&3): linear LDS dest + pre-swizzled
// global source (global_load_lds constraint), same XOR on fragment reads.
// Pipeline: 3 LDS buffers, staged 2 tiles ahead, counted s_waitcnt vmcnt(8)
// (never 0 in main loop). Barrier #1 after vmcnt: tile t resident. Barrier #2
// after MFMA (sched_barrier-pinned): all waves done reading buf before its
// reuse as a stage target next iteration.
// MODE 0: write bf16 row-major [n][768] (pre-LN activations incl. bias)
// MODE 1: write f32 NCHW out[b][o][hw] (+bias)
template <int MODE>
__global__ __launch_bounds__(256) void gemm_kernel(
    const bf16* __restrict__ A,   // [M][768] row-major
    const bf16* __restrict__ Bw,  // [768][768] = W[o][c]
    const float* __restrict__ bias,
    void* __restrict__ out)
{
    constexpr int K = DIM;
    __shared__ bf16 As[3][128][32];
    __shared__ bf16 Bs[3][128][32];

    const int t = threadIdx.x;
    const int lane = t & 63;
    const int wave = t >> 6;
    const int wr = wave >> 1, wc = wave & 1;
    const int m0 = blockIdx.x * 128;
    const int n0 = blockIdx.y * 128;

    f32x4 acc[4][4] = {};

    const int srow = t >> 2;        // 0..63
    const int glin = t & 3;         // linear 16B block within row
    const int fr = lane & 15;
    const int kb = (lane >> 4) * 4; // 0,4,8,12

    // fragment-read swizzled element offsets (depend only on lane)
    const int s_rd = (fr >> 1) & 3;
    const int g0 = kb >> 3;         // 0,0,1,1
    const int rem = kb & 7;         // 0,4,0,4
    const int offLo = ((g0 ^ s_rd) << 3) + rem;
    const int offHi = (((g0 + 2) ^ s_rd) << 3) + rem;

    auto stage = [&](int kt, int buf) {
        const int k0 = kt * 32;
#pragma unroll
        for (int i = 0; i < 2; i++) {
            const int r = srow + i * 64;
            const int gsrc = glin ^ ((r >> 1) & 3);
            __builtin_amdgcn_global_load_lds(
                (const __attribute__((address_space(1))) void*)(A + (size_t)(m0 + r) * K + k0 + gsrc * 8),
                (__attribute__((address_space(3))) void*)&As[buf][r][glin * 8], 16, 0, 0);
            __builtin_amdgcn_global_load_lds(
                (const __attribute__((address_space(1))) void*)(Bw + (size_t)(n0 + r) * K + k0 + gsrc * 8),
                (__attribute__((address_space(3))) void*)&Bs[buf][r][glin * 8], 16, 0, 0);
        }
    };

    // prologue: 2 tiles in flight
    stage(0, 0);
    stage(1, 1);

    int c0 = 0, c1 = 1, c2 = 2;
    for (int kt = 0; kt < NT; ++kt) {
        if (kt < NT - 2) {
            stage(kt + 2, c2);
            asm volatile("s_waitcnt vmcnt(8)" ::: "memory");   // tile kt resident; kt+1,kt+2 in flight
        } else if (kt == NT - 2) {
            asm volatile("s_waitcnt vmcnt(4)" ::: "memory");   // tile NT-2 resident
        } else {
            asm volatile("s_waitcnt vmcnt(0)" ::: "memory");   // tile NT-1 resident
        }
        __builtin_amdgcn_s_barrier();
        __builtin_amdgcn_sched_barrier(0);

        bf16x8 aF[4], bF[4];
#pragma unroll
        for (int mi = 0; mi < 4; mi++) {
            const bf16* p = &As[c0][wr * 64 + mi * 16 + fr][0];
            bf16x4 lo = *(const bf16x4*)(p + offLo);
            bf16x4 hi = *(const bf16x4*)(p + offHi);
            aF[mi] = __builtin_shufflevector(lo, hi, 0, 1, 2, 3, 4, 5, 6, 7);
        }
#pragma unroll
        for (int ni = 0; ni < 4; ni++) {
            const bf16* p = &Bs[c0][wc * 64 + ni * 16 + fr][0];
            bf16x4 lo = *(const bf16x4*)(p + offLo);
            bf16x4 hi = *(const bf16x4*)(p + offHi);
            bF[ni] = __builtin_shufflevector(lo, hi, 0, 1, 2, 3, 4, 5, 6, 7);
        }
        __builtin_amdgcn_s_setprio(1);
#pragma unroll
        for (int mi = 0; mi < 4; mi++)
#pragma unroll
            for (int ni = 0; ni < 4; ni++)
                acc[mi][ni] = __builtin_amdgcn_mfma_f32_16x16x32_bf16(aF[mi], bF[ni], acc[mi][ni], 0, 0, 0);
        __builtin_amdgcn_s_setprio(0);
        __builtin_amdgcn_sched_barrier(0);   // pin reads+MFMA (and their lgkm waits) before barrier #2
        __builtin_amdgcn_s_barrier();        // WAR: buf c0 reusable as stage target next iter

        const int tmp = c0; c0 = c1; c1 = c2; c2 = tmp;
    }

    const int fq = lane >> 4;  // 0..3
    if (MODE == 0) {
        bf16* o = (bf16*)out;
#pragma unroll
        for (int mi = 0; mi < 4; mi++) {
            const int row = m0 + wr * 64 + mi * 16 + fq * 4;
#pragma unroll
            for (int ni = 0; ni < 4; ni++) {
                const int col = n0 + wc * 64 + ni * 16 + fr;
                const float bv = bias[col];
#pragma unroll
                for (int r = 0; r < 4; r++)
                    o[(size_t)(row + r) * DIM + col] = (bf16)(acc[mi][ni][r] + bv);
            }
        }
    } else {
        float* o = (float*)out;
#pragma unroll
        for (int mi = 0; mi < 4; mi++) {
            const int n_base = m0 + wr * 64 + mi * 16 + fq * 4;
            const int b = n_base >> 10;
            const int hw = n_base & 1023;
#pragma unroll
            for (int ni = 0; ni < 4; ni++) {
                const int col = n0 + wc * 64 + ni * 16 + fr;
                const float bv = bias[col];
                f32x4 v = acc[mi][ni] + bv;
                *(f32x4*)(o + ((size_t)b * DIM + col) * HW + hw) = v;
            }
        }
    }
}

// ---------------- LayerNorm + exact GELU, in-place on bf16 rows ----------------
__global__ __launch_bounds__(256) void ln_gelu_kernel(
    bf16* __restrict__ h, const float* __restrict__ g, const float* __restrict__ beta)
{
    const int wave = threadIdx.x >> 6;
    const int lane = threadIdx.x & 63;
    const int n = blockIdx.x * 4 + wave;
    bf16* row = h + (size_t)n * DIM;

    float v[12];
    float s = 0.f, ss = 0.f;
#pragma unroll
    for (int j = 0; j < 3; j++) {
        bf16x4 x = *(const bf16x4*)(row + j * 256 + lane * 4);
#pragma unroll
        for (int i = 0; i < 4; i++) {
            float f = (float)x[i];
            v[j * 4 + i] = f;
            s += f;
            ss += f * f;
        }
    }
#pragma unroll
    for (int off = 32; off > 0; off >>= 1) {
        s += __shfl_xor(s, off);
        ss += __shfl_xor(ss, off);
    }
    const float mu = s * (1.f / DIM);
    const float var = ss * (1.f / DIM) - mu * mu;
    const float rstd = rsqrtf(var + 1e-6f);

#pragma unroll
    for (int j = 0; j < 3; j++) {
        bf16x4 r;
#pragma unroll
        for (int i = 0; i < 4; i++) {
            const int c = j * 256 + lane * 4 + i;
            float y = (v[j * 4 + i] - mu) * rstd * g[c] + beta[c];
            y = 0.5f * y * (1.f + erff(y * 0.70710678118f));
            r[i] = (bf16)y;
        }
        *(bf16x4*)(row + j * 256 + lane * 4) = r;
    }
}

extern "C" void kernel_launch(void* const* d_in, const int* in_sizes, int n_in,
                              void* d_out, int out_size, void* d_ws, size_t ws_size,
                              hipStream_t stream) {
    const float* x   = (const float*)d_in[0];
    const float* W1  = (const float*)d_in[1];
    const float* b1  = (const float*)d_in[2];
    const float* g1  = (const float*)d_in[3];
    const float* be1 = (const float*)d_in[4];
    const float* W2  = (const float*)d_in[5];
    const float* b2  = (const float*)d_in[6];
    const float* g2  = (const float*)d_in[7];
    const float* be2 = (const float*)d_in[8];
    const float* W3  = (const float*)d_in[9];
    const float* b3  = (const float*)d_in[10];
    float* out = (float*)d_out;

    bf16* Wb1  = (bf16*)d_ws;
    bf16* Wb2  = Wb1 + (size_t)DIM * DIM;
    bf16* Wb3  = Wb2 + (size_t)DIM * DIM;
    bf16* buf0 = Wb3 + (size_t)DIM * DIM;          // 16384*768 bf16
    bf16* buf1 = buf0 + (size_t)M_TOTAL * DIM;

    // weights -> bf16 (single launch)
    wcvt3_kernel<<<1728, 256, 0, stream>>>((const float4*)W1, (const float4*)W2, (const float4*)W3,
                                           (bf16x4*)Wb1, (bf16x4*)Wb2, (bf16x4*)Wb3);

    // x NCHW -> [n][c] bf16
    transpose_cvt_kernel<<<dim3(32, 24, 16), dim3(32, 8), 0, stream>>>(x, buf0);

    dim3 ggrid(M_TOTAL / 128, DIM / 128);
    // layer 1
    gemm_kernel<0><<<ggrid, 256, 0, stream>>>(buf0, Wb1, b1, buf1);
    ln_gelu_kernel<<<M_TOTAL / 4, 256, 0, stream>>>(buf1, g1, be1);
    // layer 2
    gemm_kernel<0><<<ggrid, 256, 0, stream>>>(buf1, Wb2, b2, buf0);
    ln_gelu_kernel<<<M_TOTAL / 4, 256, 0, stream>>>(buf0, g2, be2);
    // layer 3 -> NCHW f32 output
    gemm_kernel<1><<<ggrid, 256, 0, stream>>>(buf0, Wb3, b3, out);
}

// Round 4
// 158.648 us; speedup vs baseline: 1.8680x; 1.0783x over previous
//
#include <hip/hip_runtime.h>
#include <hip/hip_bf16.h>

typedef __bf16 bf16;
typedef __bf16 bf16x4 __attribute__((ext_vector_type(4)));
typedef __bf16 bf16x8 __attribute__((ext_vector_type(8)));
typedef float f32x4 __attribute__((ext_vector_type(4)));

#define DIM 768
#define HW 1024          // 32*32
#define BATCH 16
#define M_TOTAL (BATCH * HW)   // 16384
#define NKT 12                 // K-tiles of 64

#define AS1 __attribute__((address_space(1)))
#define AS3 __attribute__((address_space(3)))

// ======================== k-permutation convention =========================
// All bf16 [.][768] activation buffers and Wb[768][768] store the k (channel)
// dimension permuted within each 32-group: physical position p = 8g+j holds
// logical k = 4g + j (j<4) or 4g + 12 + j (j>=4).  This makes the
// mfma_f32_16x16x32_bf16 fragment (lane: k in {4q..4q+3} u {4q+16..4q+19},
// q=lane>>4) CONTIGUOUS 16B in LDS -> single ds_read_b128 per fragment.
// Dot products over k are permutation-invariant; W rows (output chan) linear.

// ---------------- weight convert: f32 -> bf16, k-permuted ----------------
__global__ void wcvt3_kernel(const float4* __restrict__ w1, const float4* __restrict__ w2,
                             const float4* __restrict__ w3,
                             bf16x8* __restrict__ o1, bf16x8* __restrict__ o2,
                             bf16x8* __restrict__ o3) {
    const int b = blockIdx.x;              // 0..863
    const int which = b / 288;
    const int i = (b % 288) * 256 + threadIdx.x;   // 0..73727 output 16B blocks
    const float4* w = which == 0 ? w1 : which == 1 ? w2 : w3;
    bf16x8* o = which == 0 ? o1 : which == 1 ? o2 : o3;
    const int row = i / 96, br = i % 96;   // 96 blocks per 768-row
    const int q = br >> 2, g = br & 3;     // 32-group, block-in-group
    float4 lo = w[row * 192 + q * 8 + g];        // k = 32q + 4g .. +3
    float4 hi = w[row * 192 + q * 8 + g + 4];    // k = 32q + 4g + 16 .. +3
    bf16x8 r = { (bf16)lo.x, (bf16)lo.y, (bf16)lo.z, (bf16)lo.w,
                 (bf16)hi.x, (bf16)hi.y, (bf16)hi.z, (bf16)hi.w };
    o[row * 96 + br] = r;
}

// ------- transpose + convert: x[16][768][1024] f32 -> xb[16384][768p] bf16 -------
__global__ void transpose_cvt_kernel(const float* __restrict__ x, bf16* __restrict__ xb) {
    __shared__ float tile[32][33];
    const int b = blockIdx.z;
    const int hw0 = blockIdx.x * 32;
    const int c0 = blockIdx.y * 32;
    const int tx = threadIdx.x, ty = threadIdx.y;  // 32 x 8

    const float* src = x + ((size_t)b * DIM + c0) * HW + hw0;
#pragma unroll
    for (int j = 0; j < 4; j++)
        tile[ty + 8 * j][tx] = src[(size_t)(ty + 8 * j) * HW + tx];
    __syncthreads();
    // k2pos(tx) within the 32-group
    const int ptx = (((tx & 15) >> 2) << 3) + (tx & 3) + ((tx >> 4) << 2);
    bf16* dst = xb + ((size_t)b * HW + hw0) * DIM + c0;
#pragma unroll
    for (int j = 0; j < 4; j++)
        dst[(size_t)(ty + 8 * j) * DIM + ptx] = (bf16)tile[tx][ty + 8 * j];
}

// ---------------- GEMM: 256x256 tile, BK=64, 8 waves, 8-phase schedule ----------------
// MODE 0: write bf16 [n][768] k-permuted (+bias). MODE 1: write f32 NCHW (+bias).
template <int MODE>
__global__ __launch_bounds__(512, 2) void gemm_kernel(
    const bf16* __restrict__ A,   // [M][768] k-permuted
    const bf16* __restrict__ Bw,  // [768][768] rows linear, cols k-permuted
    const float* __restrict__ bias,
    void* __restrict__ out)
{
    constexpr int K = DIM;
    __shared__ bf16 lds[2][2][256][64];   // [dbuf][A/B][row][k] = 128 KiB

    const int t = threadIdx.x;
    const int lane = t & 63;
    const int wave = t >> 6;
    const int wm = wave >> 2, wn = wave & 3;   // 2 x 4 waves

    const int bid = blockIdx.x;                 // 192 blocks, 192%8==0
    const int swz = (bid & 7) * 24 + (bid >> 3);
    const int m0 = (swz % 64) * 256;
    const int n0 = (swz / 64) * 256;

    const int fr = lane & 15;
    const int fq = lane >> 4;

    f32x4 acc[8][4] = {};

    const int s_r = t >> 3;     // 0..63, staging row (per j +64)
    const int s_blk = t & 7;    // staging 16B block in row

    // half-tile stage: 2 x global_load_lds, LDS dest linear (== lane*16/wave),
    // source pre-swizzled with blk ^= (row&7)  (both-sides-or-neither, G21)
    auto stage_half = [&](int kt, int which, int half) {
        const int d = kt & 1;
        const bf16* src = which == 0 ? A : Bw;
        const int row0 = which == 0 ? m0 : n0;
#pragma unroll
        for (int j = 0; j < 2; j++) {
            const int r = s_r + j * 64;         // 0..127
            const int R = half * 128 + r;
            __builtin_amdgcn_global_load_lds(
                (const AS1 void*)(src + (size_t)(row0 + R) * K + kt * 64 + ((s_blk ^ (r & 7)) << 3)),
                (AS3 void*)&lds[d][which][R][s_blk * 8], 16, 0, 0);
        }
    };

    bf16x8 a[8], b0[4], b1[4];

    auto ldA = [&](int kt, int mh) {   // 8 x ds_read_b128
        const int d = kt & 1;
#pragma unroll
        for (int mi = 0; mi < 4; mi++) {
            const int R = wm * 128 + (mh * 4 + mi) * 16 + fr;
            const bf16* rp = &lds[d][0][R][0];
            const int s = R & 7;
#pragma unroll
            for (int ks = 0; ks < 2; ks++)
                a[mi * 2 + ks] = *(const bf16x8*)(rp + (((ks * 4 + fq) ^ s) << 3));
        }
    };
    auto ldB = [&](bf16x8* bb, int kt, int nh) {   // 4 x ds_read_b128
        const int d = kt & 1;
#pragma unroll
        for (int ni = 0; ni < 2; ni++) {
            const int R = wn * 64 + (nh * 2 + ni) * 16 + fr;
            const bf16* rp = &lds[d][1][R][0];
            const int s = R & 7;
#pragma unroll
            for (int ks = 0; ks < 2; ks++)
                bb[ni * 2 + ks] = *(const bf16x8*)(rp + (((ks * 4 + fq) ^ s) << 3));
        }
    };
    auto MM = [&](bf16x8* bb, int mh, int nh) {    // 16 MFMA, setprio-wrapped (T5)
        __builtin_amdgcn_s_setprio(1);
#pragma unroll
        for (int mi = 0; mi < 4; mi++)
#pragma unroll
            for (int ni = 0; ni < 2; ni++)
#pragma unroll
                for (int ks = 0; ks < 2; ks++)
                    acc[mh * 4 + mi][nh * 2 + ni] = __builtin_amdgcn_mfma_f32_16x16x32_bf16(
                        a[mi * 2 + ks], bb[ni * 2 + ks], acc[mh * 4 + mi][nh * 2 + ni], 0, 0, 0);
        __builtin_amdgcn_s_setprio(0);
    };

    // prologue: kt0 fully + kt1's A-h0; vmcnt(2) -> kt0 resident, kt1-Ah0 in flight
    stage_half(0, 0, 0); stage_half(0, 0, 1); stage_half(0, 1, 0); stage_half(0, 1, 1);
    stage_half(1, 0, 0);
    asm volatile("s_waitcnt vmcnt(2)" ::: "memory");
    __builtin_amdgcn_s_barrier();

    for (int kt = 0; kt < NKT; ++kt) {
        // P0: quadrant (mh0, nh0); stage (kt+1, A-h1) into other dbuf
        ldA(kt, 0);
        ldB(b0, kt, 0);
        if (kt + 1 < NKT) stage_half(kt + 1, 0, 1);
        __builtin_amdgcn_s_barrier();
        asm volatile("s_waitcnt lgkmcnt(0)" ::: "memory");
        MM(b0, 0, 0);
        __builtin_amdgcn_s_barrier();
        // P1: (mh0, nh1); stage (kt+1, B-h0)
        ldB(b1, kt, 1);
        if (kt + 1 < NKT) stage_half(kt + 1, 1, 0);
        __builtin_amdgcn_s_barrier();
        asm volatile("s_waitcnt lgkmcnt(0)" ::: "memory");
        MM(b1, 0, 1);
        __builtin_amdgcn_s_barrier();
        // P2: (mh1, nh1); stage (kt+1, B-h1); last ds_reads of this dbuf
        ldA(kt, 1);
        if (kt + 1 < NKT) stage_half(kt + 1, 1, 1);
        __builtin_amdgcn_s_barrier();
        asm volatile("s_waitcnt lgkmcnt(0)" ::: "memory");
        MM(b1, 1, 1);
        __builtin_amdgcn_s_barrier();
        // P3: (mh1, nh0) from registers; stage (kt+2, A-h0) into the dbuf just
        // freed (all reads completed before P2-end barrier). Counted vmcnt:
        // keep only the newest half-tile (kt+2,A-h0) in flight -> kt+1 resident.
        if (kt + 2 < NKT) stage_half(kt + 2, 0, 0);
        MM(b0, 1, 0);
        if (kt < NKT - 2) { asm volatile("s_waitcnt vmcnt(2)" ::: "memory"); }
        else if (kt == NKT - 2) { asm volatile("s_waitcnt vmcnt(0)" ::: "memory"); }
        __builtin_amdgcn_s_barrier();
    }

    // ---------------- epilogue ----------------
    const int fq4 = fq * 4;
    if (MODE == 0) {
        bf16* o = (bf16*)out;
#pragma unroll
        for (int mi = 0; mi < 8; mi++) {
            const int row = m0 + wm * 128 + mi * 16 + fq4;
#pragma unroll
            for (int ni = 0; ni < 4; ni++) {
                const int col = n0 + wn * 64 + ni * 16 + fr;   // logical channel
                const int pcol = n0 + wn * 64 + ((ni >> 1) << 5)
                               + ((fr >> 2) << 3) + (fr & 3) + ((ni & 1) << 2); // k2pos
                const float bv = bias[col];
#pragma unroll
                for (int r = 0; r < 4; r++)
                    o[(size_t)(row + r) * DIM + pcol] = (bf16)(acc[mi][ni][r] + bv);
            }
        }
    } else {
        float* o = (float*)out;
#pragma unroll
        for (int mi = 0; mi < 8; mi++) {
            const int nb = m0 + wm * 128 + mi * 16 + fq4;
            const int bI = nb >> 10, hw = nb & 1023;
#pragma unroll
            for (int ni = 0; ni < 4; ni++) {
                const int col = n0 + wn * 64 + ni * 16 + fr;
                f32x4 v = acc[mi][ni] + bias[col];
                *(f32x4*)(o + ((size_t)bI * DIM + col) * HW + hw) = v;
            }
        }
    }
}

// ---------------- LayerNorm + exact GELU, in-place on k-permuted bf16 rows ----------------
__global__ __launch_bounds__(256) void ln_gelu_kernel(
    bf16* __restrict__ h, const float* __restrict__ g, const float* __restrict__ beta)
{
    const int wave = threadIdx.x >> 6;
    const int lane = threadIdx.x & 63;
    const int n = blockIdx.x * 4 + wave;
    bf16* row = h + (size_t)n * DIM;

    float v[12];
    float s = 0.f, ss = 0.f;
#pragma unroll
    for (int j = 0; j < 3; j++) {
        bf16x4 x = *(const bf16x4*)(row + j * 256 + lane * 4);
#pragma unroll
        for (int i = 0; i < 4; i++) {
            float f = (float)x[i];
            v[j * 4 + i] = f;
            s += f;
            ss += f * f;
        }
    }
#pragma unroll
    for (int off = 32; off > 0; off >>= 1) {
        s += __shfl_xor(s, off);
        ss += __shfl_xor(ss, off);
    }
    const float mu = s * (1.f / DIM);
    const float var = ss * (1.f / DIM) - mu * mu;
    const float rstd = rsqrtf(var + 1e-6f);

#pragma unroll
    for (int j = 0; j < 3; j++) {
        bf16x4 r;
#pragma unroll
        for (int i = 0; i < 4; i++) {
            const int c = j * 256 + lane * 4 + i;   // physical position
            const int p = (lane * 4 + i) & 31;
            const int kk = ((p >> 3) << 2) + (p & 7) + ((p & 4) ? 12 : 0);  // pos2k
            const int gi = (c & ~31) + kk;          // logical channel for gamma/beta
            float y = (v[j * 4 + i] - mu) * rstd * g[gi] + beta[gi];
            y = 0.5f * y * (1.f + erff(y * 0.70710678118f));
            r[i] = (bf16)y;
        }
        *(bf16x4*)(row + j * 256 + lane * 4) = r;
    }
}

extern "C" void kernel_launch(void* const* d_in, const int* in_sizes, int n_in,
                              void* d_out, int out_size, void* d_ws, size_t ws_size,
                              hipStream_t stream) {
    const float* x   = (const float*)d_in[0];
    const float* W1  = (const float*)d_in[1];
    const float* b1  = (const float*)d_in[2];
    const float* g1  = (const float*)d_in[3];
    const float* be1 = (const float*)d_in[4];
    const float* W2  = (const float*)d_in[5];
    const float* b2  = (const float*)d_in[6];
    const float* g2  = (const float*)d_in[7];
    const float* be2 = (const float*)d_in[8];
    const float* W3  = (const float*)d_in[9];
    const float* b3  = (const float*)d_in[10];
    float* out = (float*)d_out;

    bf16* Wb1  = (bf16*)d_ws;
    bf16* Wb2  = Wb1 + (size_t)DIM * DIM;
    bf16* Wb3  = Wb2 + (size_t)DIM * DIM;
    bf16* buf0 = Wb3 + (size_t)DIM * DIM;          // 16384*768 bf16
    bf16* buf1 = buf0 + (size_t)M_TOTAL * DIM;

    // weights -> bf16 k-permuted (single launch)
    wcvt3_kernel<<<864, 256, 0, stream>>>((const float4*)W1, (const float4*)W2, (const float4*)W3,
                                          (bf16x8*)Wb1, (bf16x8*)Wb2, (bf16x8*)Wb3);

    // x NCHW -> [n][c] bf16 k-permuted
    transpose_cvt_kernel<<<dim3(32, 24, 16), dim3(32, 8), 0, stream>>>(x, buf0);

    const int ggrid = (M_TOTAL / 256) * (DIM / 256);   // 64*3 = 192
    // layer 1
    gemm_kernel<0><<<ggrid, 512, 0, stream>>>(buf0, Wb1, b1, buf1);
    ln_gelu_kernel<<<M_TOTAL / 4, 256, 0, stream>>>(buf1, g1, be1);
    // layer 2
    gemm_kernel<0><<<ggrid, 512, 0, stream>>>(buf1, Wb2, b2, buf0);
    ln_gelu_kernel<<<M_TOTAL / 4, 256, 0, stream>>>(buf0, g2, be2);
    // layer 3 -> NCHW f32 output
    gemm_kernel<1><<<ggrid, 512, 0, stream>>>(buf0, Wb3, b3, out);
}